// Round 1
// baseline (1425.735 us; speedup 1.0000x reference)
//
#include <hip/hip_runtime.h>

typedef __bf16 bf16;
typedef __attribute__((ext_vector_type(8))) __bf16 bf16x8;
typedef __attribute__((ext_vector_type(4))) __bf16 bf16x4;
typedef __attribute__((ext_vector_type(4))) float f32x4;

#define SCALE 0.17677669529663687f   // 1/sqrt(32)

__device__ __forceinline__ f32x4 mfma16(bf16x8 a, bf16x8 b, f32x4 c) {
  return __builtin_amdgcn_mfma_f32_16x16x32_bf16(a, b, c, 0, 0, 0);
}

// ---------------------------------------------------------------------------
// prep: wt[c][k] = bf16(w_qkv[k][c])  (512x1536 -> 1536x512, row-major in k)
//       wpt[c][k] = bf16(w_proj[k][c]) (512x512)
// Gives B-operand fragments as contiguous 16B loads (lane: col=l&15, k=quad*8+j).
// ---------------------------------------------------------------------------
__global__ void prep_weights(const float* __restrict__ w_qkv,
                             const float* __restrict__ w_proj,
                             bf16* __restrict__ wt, bf16* __restrict__ wpt) {
  __shared__ float tile[32][33];
  int b = blockIdx.x;
  const float* src; bf16* dst; int C, tk, tc;
  if (b < 768) {            // 16 k-tiles x 48 c-tiles
    src = w_qkv; dst = wt; C = 1536; tk = (b & 15) * 32; tc = (b >> 4) * 32;
  } else {                  // 16 x 16 tiles
    b -= 768; src = w_proj; dst = wpt; C = 512; tk = (b & 15) * 32; tc = (b >> 4) * 32;
  }
  int tx = threadIdx.x & 31, ty = threadIdx.x >> 5;
#pragma unroll
  for (int i = 0; i < 4; i++)
    tile[ty + i * 8][tx] = src[(size_t)(tk + ty + i * 8) * C + tc + tx];
  __syncthreads();
#pragma unroll
  for (int i = 0; i < 4; i++)
    dst[(size_t)(tc + ty + i * 8) * 512 + tk + tx] = (bf16)tile[tx][ty + i * 8];
}

// ---------------------------------------------------------------------------
// Fused window attention: one block (4 waves) per window.
// MFMA 16x16x32 bf16 layouts (HW-verified, learn_hip m89/m120):
//   A: lane holds A[m=l&15][k=quad*8+j]   (16B contiguous if row-major in k)
//   B: lane holds B[k=quad*8+j][n=l&15]
//   C: lane holds C[row=quad*4+r][col=l&15]
// ---------------------------------------------------------------------------
__launch_bounds__(256, 1)
__global__ void ewattn(const float* __restrict__ x,
                       const float* __restrict__ b_qkv,
                       const float* __restrict__ w_k,
                       const float* __restrict__ w_v,
                       const float* __restrict__ bias_table,
                       const float* __restrict__ b_proj,
                       const bf16* __restrict__ wt,
                       const bf16* __restrict__ wpt,
                       float* __restrict__ out) {
  // LDS budget: 66560 + 16640*2 + 2304*2 + 128 + 20480 + 5120 + 10240 = 140416 B
  __shared__ bf16 xs[64][520];      // phase A/B: bf16(x); phase C/D: reused as ao (head outs)
  __shared__ bf16 xk[16][520];      // w_k @ x
  __shared__ bf16 xv[16][520];      // w_v @ x
  __shared__ bf16 wkl[16][72];
  __shared__ bf16 wvl[16][72];
  __shared__ float rs[32];          // rowsum(w_k)[16], rowsum(w_v)[16]
  __shared__ bf16 qs[4][64][40];    // per-wave: q staging, then attn-prob staging
  __shared__ bf16 kps[4][16][40];   // per-wave: k_proj [p][d]
  __shared__ bf16 vpt[4][32][40];   // per-wave: v_proj^T [d][p], p in [16,32) stays 0 (K-pad)

  const int tid  = threadIdx.x;
  const int lane = tid & 63;
  const int wid  = tid >> 6;        // wave 0..3 -> heads 4w..4w+3, cols [128w,128w+128)
  const int l15  = lane & 15;
  const int quad = lane >> 4;
  const int win  = blockIdx.x;
  const float* xw = x + (size_t)win * (64 * 512);

  // ---------------- Phase A: stage inputs ----------------
  for (int i = tid; i < 8192; i += 256) {           // 64*512/4 float4s
    int idx = i * 4;
    int r = idx >> 9, c = idx & 511;
    float4 v = *reinterpret_cast<const float4*>(xw + idx);
    xs[r][c]     = (bf16)v.x; xs[r][c + 1] = (bf16)v.y;
    xs[r][c + 2] = (bf16)v.z; xs[r][c + 3] = (bf16)v.w;
  }
  for (int i = tid; i < 1024; i += 256) {
    int p = i >> 6, n = i & 63;
    wkl[p][n] = (bf16)w_k[i];
    wvl[p][n] = (bf16)w_v[i];
  }
  if (tid < 16) {
    float sk = 0.f, sv = 0.f;
#pragma unroll
    for (int n = 0; n < 64; n++) { sk += w_k[tid * 64 + n]; sv += w_v[tid * 64 + n]; }
    rs[tid] = sk; rs[16 + tid] = sv;
  }
  for (int i = tid; i < 4 * 32 * 40; i += 256)      // zero vpt (K-pad region must be 0, not NaN)
    ((bf16*)vpt)[i] = (bf16)0.0f;
  __syncthreads();

  // ---------------- Phase B ----------------
  // B2: xk = wk @ xs, xv = wv @ xs  (out [16][512]; this wave's 8 col-tiles)
  {
    f32x4 ak[8], av[8];
#pragma unroll
    for (int i = 0; i < 8; i++) { ak[i] = f32x4{0.f,0.f,0.f,0.f}; av[i] = f32x4{0.f,0.f,0.f,0.f}; }
#pragma unroll
    for (int kt = 0; kt < 2; kt++) {
      bf16x8 aK = *(const bf16x8*)&wkl[l15][kt * 32 + quad * 8];
      bf16x8 aV = *(const bf16x8*)&wvl[l15][kt * 32 + quad * 8];
      int n0 = kt * 32 + quad * 8;
#pragma unroll
      for (int nt = 0; nt < 8; nt++) {
        int c = wid * 128 + nt * 16 + l15;
        bf16x8 bb;                                   // B[k=n][c] = xs[n][c] (column walk)
#pragma unroll
        for (int j = 0; j < 8; j++) bb[j] = xs[n0 + j][c];
        ak[nt] = mfma16(aK, bb, ak[nt]);
        av[nt] = mfma16(aV, bb, av[nt]);
      }
    }
#pragma unroll
    for (int nt = 0; nt < 8; nt++) {
      int c = wid * 128 + nt * 16 + l15;
#pragma unroll
      for (int r = 0; r < 4; r++) {
        xk[quad * 4 + r][c] = (bf16)ak[nt][r];
        xv[quad * 4 + r][c] = (bf16)av[nt][r];
      }
    }
  }

  // B1: q (this wave's 128 cols) = xs @ wt[:512] ; scale+bias folded; pack to bf16 regs
  bf16x4 qb[8][4];
  {
    f32x4 qacc[8][4];
#pragma unroll
    for (int nt = 0; nt < 8; nt++)
#pragma unroll
      for (int mt = 0; mt < 4; mt++) qacc[nt][mt] = f32x4{0.f,0.f,0.f,0.f};
    for (int kt = 0; kt < 16; kt++) {
      bf16x8 af[4];
#pragma unroll
      for (int mt = 0; mt < 4; mt++)
        af[mt] = *(const bf16x8*)&xs[mt * 16 + l15][kt * 32 + quad * 8];
#pragma unroll
      for (int nt = 0; nt < 8; nt++) {
        int c = wid * 128 + nt * 16 + l15;
        bf16x8 bb = *(const bf16x8*)&wt[(size_t)c * 512 + kt * 32 + quad * 8];
#pragma unroll
        for (int mt = 0; mt < 4; mt++)
          qacc[nt][mt] = mfma16(af[mt], bb, qacc[nt][mt]);
      }
    }
#pragma unroll
    for (int nt = 0; nt < 8; nt++) {
      float bq = b_qkv[wid * 128 + nt * 16 + l15];
#pragma unroll
      for (int mt = 0; mt < 4; mt++)
#pragma unroll
        for (int r = 0; r < 4; r++)
          qb[nt][mt][r] = (bf16)((qacc[nt][mt][r] + bq) * SCALE);
    }
  }
  __syncthreads();   // xk/xv visible to all; xs reads done -> reusable as ao

  // ---------------- Phase C: 4 heads per wave ----------------
  for (int hi = 0; hi < 4; hi++) {
    const int h = wid * 4 + hi;

    // k_proj/v_proj [16][32] = xk/xv @ wt cols, + rowsum-folded bias
    f32x4 kp[2], vp[2];
    kp[0] = kp[1] = vp[0] = vp[1] = f32x4{0.f,0.f,0.f,0.f};
    for (int kt = 0; kt < 16; kt++) {
      bf16x8 aK = *(const bf16x8*)&xk[l15][kt * 32 + quad * 8];
      bf16x8 aV = *(const bf16x8*)&xv[l15][kt * 32 + quad * 8];
#pragma unroll
      for (int nt = 0; nt < 2; nt++) {
        int ck = 512 + h * 32 + nt * 16 + l15;
        int cv = 1024 + h * 32 + nt * 16 + l15;
        bf16x8 bk = *(const bf16x8*)&wt[(size_t)ck * 512 + kt * 32 + quad * 8];
        bf16x8 bv = *(const bf16x8*)&wt[(size_t)cv * 512 + kt * 32 + quad * 8];
        kp[nt] = mfma16(aK, bk, kp[nt]);
        vp[nt] = mfma16(aV, bv, vp[nt]);
      }
    }
#pragma unroll
    for (int nt = 0; nt < 2; nt++) {
      float bk = b_qkv[512 + h * 32 + nt * 16 + l15];
      float bv = b_qkv[1024 + h * 32 + nt * 16 + l15];
#pragma unroll
      for (int r = 0; r < 4; r++) {
        int p = quad * 4 + r;
        kps[wid][p][nt * 16 + l15] = (bf16)(kp[nt][r] + rs[p] * bk);
        vpt[wid][nt * 16 + l15][p] = (bf16)(vp[nt][r] + rs[16 + p] * bv);
      }
    }

    // stage q for this head (local d = 0..31)
#pragma unroll
    for (int nn = 0; nn < 2; nn++)
#pragma unroll
      for (int mt = 0; mt < 4; mt++)
#pragma unroll
        for (int r = 0; r < 4; r++)
          qs[wid][mt * 16 + quad * 4 + r][nn * 16 + l15] = qb[hi * 2 + nn][mt][r];

    // attn = q @ k_proj^T : [64][16], K=32 (same-wave LDS ops are ordered; compiler waitcnts)
    f32x4 at[4];
    {
      bf16x8 bk2 = *(const bf16x8*)&kps[wid][l15][quad * 8];
#pragma unroll
      for (int mt = 0; mt < 4; mt++) {
        bf16x8 aq = *(const bf16x8*)&qs[wid][mt * 16 + l15][quad * 8];
        at[mt] = mfma16(aq, bk2, f32x4{0.f,0.f,0.f,0.f});
      }
    }

    // rel-pos bias + softmax over p (row n lives in the 16 lanes of this quad)
    float pr[4][4];
#pragma unroll
    for (int mt = 0; mt < 4; mt++) {
#pragma unroll
      for (int r = 0; r < 4; r++) {
        int n = mt * 16 + quad * 4 + r;
        int rel = ((n >> 3) - (l15 >> 3) + 7) * 15 + ((n & 7) - (l15 & 7) + 7);
        float e = __expf(at[mt][r] + bias_table[rel * 16 + h]);
        float s = e;
        s += __shfl_xor(s, 1); s += __shfl_xor(s, 2);
        s += __shfl_xor(s, 4); s += __shfl_xor(s, 8);
        pr[mt][r] = e * __builtin_amdgcn_rcpf(s);
      }
    }

    // probs -> qs cols 0..15 (cols 16..31 = stale q, finite; multiplied by vpt zeros)
#pragma unroll
    for (int mt = 0; mt < 4; mt++)
#pragma unroll
      for (int r = 0; r < 4; r++)
        qs[wid][mt * 16 + quad * 4 + r][l15] = (bf16)pr[mt][r];

    // out_head [64][32] = probs @ v_proj  (K padded to 32)
    f32x4 ov[2][4];
#pragma unroll
    for (int nd = 0; nd < 2; nd++) {
      bf16x8 bv2 = *(const bf16x8*)&vpt[wid][nd * 16 + l15][quad * 8];
#pragma unroll
      for (int mt = 0; mt < 4; mt++) {
        bf16x8 ap = *(const bf16x8*)&qs[wid][mt * 16 + l15][quad * 8];
        ov[nd][mt] = mfma16(ap, bv2, f32x4{0.f,0.f,0.f,0.f});
      }
    }
    // write head output into ao (= xs buffer), cols h*32..h*32+31
#pragma unroll
    for (int nd = 0; nd < 2; nd++)
#pragma unroll
      for (int mt = 0; mt < 4; mt++)
#pragma unroll
        for (int r = 0; r < 4; r++)
          xs[mt * 16 + quad * 4 + r][h * 32 + nd * 16 + l15] = (bf16)ov[nd][mt][r];
  }
  __syncthreads();   // all heads' ao written

  // ---------------- Phase D: out = ao @ w_proj + b_proj ----------------
  {
    f32x4 oacc[8][4];
#pragma unroll
    for (int nt = 0; nt < 8; nt++)
#pragma unroll
      for (int mt = 0; mt < 4; mt++) oacc[nt][mt] = f32x4{0.f,0.f,0.f,0.f};
    for (int kt = 0; kt < 16; kt++) {
      bf16x8 af[4];
#pragma unroll
      for (int mt = 0; mt < 4; mt++)
        af[mt] = *(const bf16x8*)&xs[mt * 16 + l15][kt * 32 + quad * 8];
#pragma unroll
      for (int nt = 0; nt < 8; nt++) {
        int c = wid * 128 + nt * 16 + l15;
        bf16x8 bb = *(const bf16x8*)&wpt[(size_t)c * 512 + kt * 32 + quad * 8];
#pragma unroll
        for (int mt = 0; mt < 4; mt++)
          oacc[nt][mt] = mfma16(af[mt], bb, oacc[nt][mt]);
      }
    }
    float* ow = out + (size_t)win * (64 * 512);
#pragma unroll
    for (int nt = 0; nt < 8; nt++) {
      int c = wid * 128 + nt * 16 + l15;
      float bp = b_proj[c];
#pragma unroll
      for (int mt = 0; mt < 4; mt++)
#pragma unroll
        for (int r = 0; r < 4; r++)
          ow[(size_t)(mt * 16 + quad * 4 + r) * 512 + c] = oacc[nt][mt][r] + bp;
    }
  }
}

extern "C" void kernel_launch(void* const* d_in, const int* in_sizes, int n_in,
                              void* d_out, int out_size, void* d_ws, size_t ws_size,
                              hipStream_t stream) {
  const float* x          = (const float*)d_in[0];
  const float* w_qkv      = (const float*)d_in[1];
  const float* b_qkv      = (const float*)d_in[2];
  const float* w_proj     = (const float*)d_in[3];
  const float* b_proj     = (const float*)d_in[4];
  const float* w_k        = (const float*)d_in[5];
  const float* w_v        = (const float*)d_in[6];
  const float* bias_table = (const float*)d_in[7];
  (void)in_sizes; (void)n_in; (void)out_size; (void)ws_size;

  bf16* wt  = (bf16*)d_ws;            // [1536][512]
  bf16* wpt = wt + 1536 * 512;        // [512][512]  (total 2 MiB of ws)

  prep_weights<<<1024, 256, 0, stream>>>(w_qkv, w_proj, wt, wpt);
  ewattn<<<2048, 256, 0, stream>>>(x, b_qkv, w_k, w_v, bias_table, b_proj,
                                   wt, wpt, (float*)d_out);
}